// Round 1
// baseline (197.784 us; speedup 1.0000x reference)
//
#include <hip/hip_runtime.h>

typedef __bf16 bf16x8 __attribute__((ext_vector_type(8)));
typedef __bf16 bf16x4 __attribute__((ext_vector_type(4)));
typedef float  f32x4  __attribute__((ext_vector_type(4)));

#define BM 128
#define BN 128
#define BK 64
#define LSD 144   // epilogue LDS stride (elems): 288B rows -> quads hit distinct bank groups, rows stay 16B-aligned

__device__ __forceinline__ void g2l16(const void* g, void* l) {
    __builtin_amdgcn_global_load_lds((const __attribute__((address_space(1))) void*)g,
                                     (__attribute__((address_space(3))) void*)l, 16, 0, 0);
}

// NT GEMM: C[i][j] = sum_k A[i*lda+k] * B[j*ldb+k]  (+ epilogue)
// 128x128 tile, BK=64, 4 waves 2x2, wave computes 64x64.
// LDS staging: unpadded [128][64] bf16, 16B-unit XOR swizzle at the global
// SOURCE column (global_load_lds needs linear dest) -> 0 bank conflicts.
// Epilogue: R5 change. Counters showed writes pinned at 1.22 TB/s across all
// replays (WRITE_SIZE/dur constant) -> write-BW-bound on fragmented stores
// (scalar bf16 = 32B half-line segments; vT bf16x4 = 8B @ 2KB stride).
// Now: acc -> LDS tile [128][LSD=144] -> bf16x8 full-line streaming stores
// (16 lanes = 256B contiguous). vT path stores the LDS tile transposed.
// EPI: 2 = exp -> bf16 row-major store                      [logits -> E]
//      4 = +bias projection; z<2 bf16 row-major (q,k), z==2 transposed vT
// SWZ: 0 = plain 3D grid.
//      1 = XCD-sequential flat grid (logits): x=id%8 is the XCD slot; within
//          an XCD, 64 consecutive s-values form ONE batch (z = x + 8*(s>>6)),
//          so each XCD streams one batch at a time: q+k working set ~4MB = L2.
template<int EPI, int SWZ>
__global__ __launch_bounds__(256)
void gemm_nt(const __bf16* __restrict__ A, const __bf16* __restrict__ B,
             void* __restrict__ Cv, const float* __restrict__ bias,
             int lda, int ldb, int ldc, int K,
             long sA, long sB, long sC)
{
    // 36864 B: staging As(16K)+Bs(16K) overlap the 128x144 epilogue tile.
    __shared__ __align__(16) __bf16 smem[128 * LSD];
    __bf16* As = smem;
    __bf16* Bs = smem + BM * BK;

    const int tid  = threadIdx.x;
    const int w    = tid >> 6;
    const int lane = tid & 63;
    const int quad = lane >> 4;
    const int l16  = lane & 15;
    const int wm   = w & 1;
    const int wn   = w >> 1;

    int m0, n0, z;
    if constexpr (SWZ == 1) {
        const int id = blockIdx.x;
        const int x  = id & 7, s = id >> 3;
        z = x + ((s >> 6) << 3);
        const int t = s & 63;
        m0 = (t & 7) * BM;
        n0 = (t >> 3) * BN;
    } else {
        m0 = blockIdx.x * BM;
        n0 = blockIdx.y * BN;
        z  = blockIdx.z;
    }

    const __bf16* Ab = A + (size_t)z * sA;
    const __bf16* Bb = B + (size_t)z * sB;

    const int srow = (w << 3) + (lane >> 3);
    const int scol = ((lane & 7) ^ (lane >> 3)) << 3;
    char* ldsA = (char*)As + (size_t)w * 1024;
    char* ldsB = (char*)Bs + (size_t)w * 1024;

    const __bf16* Ag = Ab + (size_t)(m0 + srow) * lda + scol;
    const __bf16* Bg = Bb + (size_t)(n0 + srow) * ldb + scol;

    f32x4 acc[4][4] = {};

    for (int k0 = 0; k0 < K; k0 += BK) {
        __syncthreads();
        #pragma unroll
        for (int c = 0; c < 4; c++)
            g2l16(Ag + (size_t)(c * 32) * lda + k0, ldsA + c * 4096);
        #pragma unroll
        for (int c = 0; c < 4; c++)
            g2l16(Bg + (size_t)(c * 32) * ldb + k0, ldsB + c * 4096);
        __syncthreads();

        #pragma unroll
        for (int kk = 0; kk < BK; kk += 32) {
            const int ub = kk >> 3;
            bf16x8 a[4], b[4];
            #pragma unroll
            for (int mt = 0; mt < 4; mt++) {
                const int row = wm * 64 + mt * 16 + l16;
                const int cp  = ((quad + ub) ^ (row & 7)) << 3;
                a[mt] = *(const bf16x8*)&As[row * BK + cp];
            }
            #pragma unroll
            for (int nt = 0; nt < 4; nt++) {
                const int row = wn * 64 + nt * 16 + l16;
                const int cp  = ((quad + ub) ^ (row & 7)) << 3;
                b[nt] = *(const bf16x8*)&Bs[row * BK + cp];
            }
            #pragma unroll
            for (int mt = 0; mt < 4; mt++)
                #pragma unroll
                for (int nt = 0; nt < 4; nt++)
                    acc[mt][nt] = __builtin_amdgcn_mfma_f32_16x16x32_bf16(
                        a[mt], b[nt], acc[mt][nt], 0, 0, 0);
        }
    }

    // ---- Epilogue via LDS: full-line bf16x8 streaming stores ----
    // C/D layout (m89/m91): row = quad*4 + reg, col = l16.
    __syncthreads();   // all waves done reading As/Bs before overwrite

    if constexpr (EPI == 2) {
        #pragma unroll
        for (int mt = 0; mt < 4; mt++) {
            const int rl = wm * 64 + mt * 16 + quad * 4;
            #pragma unroll
            for (int nt = 0; nt < 4; nt++) {
                const int cl = wn * 64 + nt * 16 + l16;
                #pragma unroll
                for (int r = 0; r < 4; r++)
                    smem[(rl + r) * LSD + cl] = (__bf16)__expf(acc[mt][nt][r]);
            }
        }
        __syncthreads();
        __bf16* C = (__bf16*)Cv + (size_t)z * sC;
        #pragma unroll
        for (int i = 0; i < 8; i++) {
            const int c   = tid + i * 256;          // 2048 bf16x8 chunks
            const int row = c >> 4, c8 = (c & 15) << 3;
            *(bf16x8*)&C[(size_t)(m0 + row) * ldc + n0 + c8] =
                *(const bf16x8*)&smem[row * LSD + c8];
        }
    } else {  // EPI == 4
        if (z < 2) {
            #pragma unroll
            for (int mt = 0; mt < 4; mt++) {
                const int rl = wm * 64 + mt * 16 + quad * 4;
                #pragma unroll
                for (int nt = 0; nt < 4; nt++) {
                    const int cl = wn * 64 + nt * 16 + l16;
                    const float bn = bias[z * 256 + n0 + cl];
                    #pragma unroll
                    for (int r = 0; r < 4; r++)
                        smem[(rl + r) * LSD + cl] = (__bf16)(acc[mt][nt][r] + bn);
                }
            }
            __syncthreads();
            __bf16* C = (__bf16*)Cv + (size_t)z * sC;
            #pragma unroll
            for (int i = 0; i < 8; i++) {
                const int c   = tid + i * 256;
                const int row = c >> 4, c8 = (c & 15) << 3;
                *(bf16x8*)&C[(size_t)(m0 + row) * ldc + n0 + c8] =
                    *(const bf16x8*)&smem[row * LSD + c8];
            }
        } else {
            // vT[b][d][m]: stage transposed in LDS [d_local][m_local], then
            // stream contiguous-in-m full lines.
            #pragma unroll
            for (int mt = 0; mt < 4; mt++) {
                const int ml = wm * 64 + mt * 16 + quad * 4;   // multiple of 4
                #pragma unroll
                for (int nt = 0; nt < 4; nt++) {
                    const int dl = wn * 64 + nt * 16 + l16;
                    const float bn = bias[z * 256 + n0 + dl];
                    bf16x4 pk;
                    #pragma unroll
                    for (int r = 0; r < 4; r++) pk[r] = (__bf16)(acc[mt][nt][r] + bn);
                    *(bf16x4*)&smem[dl * LSD + ml] = pk;
                }
            }
            __syncthreads();
            __bf16* C = (__bf16*)Cv + 2 * sC;
            const int bidx = m0 >> 10, mbase = m0 & 1023;
            #pragma unroll
            for (int i = 0; i < 8; i++) {
                const int c  = tid + i * 256;
                const int dl = c >> 4, m8 = (c & 15) << 3;
                *(bf16x8*)&C[(size_t)bidx * 262144 + (size_t)(n0 + dl) * 1024 + mbase + m8] =
                    *(const bf16x8*)&smem[dl * LSD + m8];
            }
        }
    }
}

// PV GEMM (plain NT, E already normalized): out[z][n,d] = attn[z] @ vT[z]^T.
// 128x64 tile -> grid 1024 = 4 blocks/CU. fp32 out stores are already
// full-line (16 lanes x 4B = 64B contiguous) -> direct stores kept.
__global__ __launch_bounds__(256)
void gemm_pv(const __bf16* __restrict__ E, const __bf16* __restrict__ vT,
             float* __restrict__ out)
{
    __shared__ __align__(16) __bf16 As[128 * 64];   // 16 KB
    __shared__ __align__(16) __bf16 Bs[64 * 64];    //  8 KB

    const int tid  = threadIdx.x;
    const int w    = tid >> 6;
    const int lane = tid & 63;
    const int quad = lane >> 4;
    const int l16  = lane & 15;
    const int wm   = w & 1;        // 64-row half
    const int wn   = w >> 1;       // 32-col half

    const int id = blockIdx.x;
    const int x  = id & 7, s = id >> 3;        // s: 0..127
    const int z  = x + ((s >> 5) << 3);        // 4 batches per XCD, sequential
    const int t  = s & 31;
    const int m0 = (t & 7) * 128;              // n-row tile
    const int n0 = (t >> 3) * 64;              // d-col tile

    const __bf16* Eb = E  + (size_t)z * 1048576;
    const __bf16* Vb = vT + (size_t)z * 262144;
    float*        Ob = out + (size_t)z * 262144;

    const int srow = (w << 3) + (lane >> 3);
    const int scol = ((lane & 7) ^ (lane >> 3)) << 3;
    char* ldsA = (char*)As + (size_t)w * 1024;
    char* ldsB = (char*)Bs + (size_t)w * 1024;

    const __bf16* Ag = Eb + (size_t)(m0 + srow) * 1024 + scol;
    const __bf16* Bg = Vb + (size_t)(n0 + srow) * 1024 + scol;

    f32x4 acc[4][2] = {};

    for (int k0 = 0; k0 < 1024; k0 += BK) {
        __syncthreads();
        #pragma unroll
        for (int c = 0; c < 4; c++)
            g2l16(Ag + (size_t)(c * 32) * 1024 + k0, ldsA + c * 4096);
        #pragma unroll
        for (int c = 0; c < 2; c++)
            g2l16(Bg + (size_t)(c * 32) * 1024 + k0, ldsB + c * 4096);
        __syncthreads();

        #pragma unroll
        for (int kk = 0; kk < BK; kk += 32) {
            const int ub = kk >> 3;
            bf16x8 a[4], b[2];
            #pragma unroll
            for (int mt = 0; mt < 4; mt++) {
                const int row = wm * 64 + mt * 16 + l16;
                const int cp  = ((quad + ub) ^ (row & 7)) << 3;
                a[mt] = *(const bf16x8*)&As[row * BK + cp];
            }
            #pragma unroll
            for (int nt = 0; nt < 2; nt++) {
                const int row = wn * 32 + nt * 16 + l16;
                const int cp  = ((quad + ub) ^ (row & 7)) << 3;
                b[nt] = *(const bf16x8*)&Bs[row * BK + cp];
            }
            #pragma unroll
            for (int mt = 0; mt < 4; mt++)
                #pragma unroll
                for (int nt = 0; nt < 2; nt++)
                    acc[mt][nt] = __builtin_amdgcn_mfma_f32_16x16x32_bf16(
                        a[mt], b[nt], acc[mt][nt], 0, 0, 0);
        }
    }

    #pragma unroll
    for (int mt = 0; mt < 4; mt++) {
        const int mb = m0 + wm * 64 + mt * 16 + quad * 4;
        #pragma unroll
        for (int nt = 0; nt < 2; nt++) {
            const int n = n0 + wn * 32 + nt * 16 + l16;
            #pragma unroll
            for (int r = 0; r < 4; r++)
                Ob[(size_t)(mb + r) * 256 + n] = acc[mt][nt][r];
        }
    }
}

// One launch: x -> bf16, Wq/Wk/Wv -> bf16, pack 3 fp32 biases.
__global__ __launch_bounds__(256)
void cvt_all(const float* __restrict__ x,
             const float* __restrict__ Wq, const float* __restrict__ Wk,
             const float* __restrict__ Wv,
             const float* __restrict__ bq, const float* __restrict__ bk,
             const float* __restrict__ bv,
             __bf16* __restrict__ xb, __bf16* __restrict__ Wqb,
             float* __restrict__ bpack)
{
    const int i = blockIdx.x * 256 + threadIdx.x;
    if (i < 1073152) {
        const float* s; __bf16* d; int off;
        if (i < 1048576)      { s = x;  d = xb;            off = i; }
        else if (i < 1056768) { s = Wq; d = Wqb;           off = i - 1048576; }
        else if (i < 1064960) { s = Wk; d = Wqb + 131072;  off = i - 1056768; }
        else                  { s = Wv; d = Wqb + 262144;  off = i - 1064960; }
        const float4* s4 = (const float4*)s;
        const float4 f0 = s4[off * 2], f1 = s4[off * 2 + 1];
        bf16x8 o;
        o[0] = (__bf16)f0.x; o[1] = (__bf16)f0.y; o[2] = (__bf16)f0.z; o[3] = (__bf16)f0.w;
        o[4] = (__bf16)f1.x; o[5] = (__bf16)f1.y; o[6] = (__bf16)f1.z; o[7] = (__bf16)f1.w;
        ((bf16x8*)d)[off] = o;
    } else if (i < 1073344) {
        const int j = i - 1073152;
        const int sel = j >> 6, jj = j & 63;
        const float* s = sel == 0 ? bq : (sel == 1 ? bk : bv);
        ((float4*)bpack)[j] = ((const float4*)s)[jj];
    }
}

// Batch-axis softmax: S[n,m] = sum_b E[b,n,m]; E <- E/S. Single pass:
// all 32 batch slices cached in registers (32 x bf16x8 = 128 VGPR).
__global__ __launch_bounds__(256)
void softmax_norm(__bf16* __restrict__ E)
{
    const size_t p = (size_t)blockIdx.x * 256 + threadIdx.x;
    bf16x8* E8 = (bf16x8*)E;
    bf16x8 e[32];
    #pragma unroll
    for (int b = 0; b < 32; b++) e[b] = E8[(size_t)b * 131072 + p];
    float s[8] = {0.f, 0.f, 0.f, 0.f, 0.f, 0.f, 0.f, 0.f};
    #pragma unroll
    for (int b = 0; b < 32; b++)
        #pragma unroll
        for (int j = 0; j < 8; j++) s[j] += (float)e[b][j];
    float rs[8];
    #pragma unroll
    for (int j = 0; j < 8; j++) rs[j] = __builtin_amdgcn_rcpf(s[j]);
    #pragma unroll
    for (int b = 0; b < 32; b++) {
        bf16x8 o = e[b];
        #pragma unroll
        for (int j = 0; j < 8; j++) o[j] = (__bf16)((float)o[j] * rs[j]);
        E8[(size_t)b * 131072 + p] = o;
    }
}

extern "C" void kernel_launch(void* const* d_in, const int* in_sizes, int n_in,
                              void* d_out, int out_size, void* d_ws, size_t ws_size,
                              hipStream_t stream)
{
    const float* x  = (const float*)d_in[0];
    const float* Wq = (const float*)d_in[1];
    const float* bq = (const float*)d_in[2];
    const float* Wk = (const float*)d_in[3];
    const float* bk = (const float*)d_in[4];
    const float* Wv = (const float*)d_in[5];
    const float* bv = (const float*)d_in[6];
    float* out = (float*)d_out;

    // Workspace layout (bytes):
    //   [0,16M)    xb   bf16 (32768x256)
    //   [16M,32M)  qb \
    //   [32M,48M)  kb  } stride 16M (8388608 elem)
    //   [48M,64M)  vT (32,256,1024)
    //   [64M,128M) E  bf16 (32,1024,1024)
    //   [128M,+768K) Wqb/Wkb/Wvb bf16 contiguous
    //   [+768K,+771K) bpack fp32[768]
    char* ws = (char*)d_ws;
    __bf16* xb    = (__bf16*)(ws);
    __bf16* qkv   = (__bf16*)(ws + (16u << 20));
    __bf16* E     = (__bf16*)(ws + (64u << 20));
    __bf16* Wqb   = (__bf16*)(ws + (128u << 20));
    float*  bpack = (float*) (ws + (128u << 20) + (3u << 18));

    // 1) converts + bias pack
    cvt_all<<<4194, 256, 0, stream>>>(x, Wq, Wk, Wv, bq, bk, bv, xb, Wqb, bpack);

    // 2) q/k/v projections, one launch (z picks W/bias/output path)
    gemm_nt<4, 0><<<dim3(256, 2, 3), 256, 0, stream>>>(xb, Wqb, qkv, bpack,
                                                       256, 256, 256, 256,
                                                       0, 131072, 8388608);

    // 3) E[b] = exp(q[b] @ k[b]^T), XCD-sequential flat grid
    gemm_nt<2, 1><<<2048, 256, 0, stream>>>(qkv, qkv + 8388608, E, nullptr,
                                            256, 256, 1024, 256,
                                            262144, 262144, 1048576);

    // 4) batch-axis softmax normalize in place (single 128MB streaming pass)
    softmax_norm<<<512, 256, 0, stream>>>(E);

    // 5) out[b] = attn[b] @ vT[b]^T, plain GEMM, 128x64 tiles, grid 1024
    gemm_pv<<<1024, 256, 0, stream>>>(E, qkv + 2 * 8388608, out);
}